// Round 14
// baseline (383.555 us; speedup 1.0000x reference)
//
#include <hip/hip_runtime.h>
#include <hip/hip_fp16.h>
#include <cstdint>

#define NN 50000
#define NE 800000
static constexpr int HD = 128;     // H*D for every layer
static constexpr int EF_DIM = 16;  // edge feature dim
static constexpr int SCAN_B = 256;
static constexpr int NPARTS = (NN + SCAN_B - 1) / SCAN_B;  // 196
static constexpr int EBLK = (NE + 255) / 256;              // 3125
static constexpr int FG = (NN + 63) / 64;                  // 782 feat blocks

typedef _Float16 f16x4 __attribute__((ext_vector_type(4)));
typedef float f32x4 __attribute__((ext_vector_type(4)));

// 32B edge payload
struct RecP {
    int src;
    int e;
    f16x4 p0;       // layer0 ep (4 heads)
    f16x4 p1;       // layer1 ep
    _Float16 p2;    // layer2 ep
    _Float16 pad;
};
union Rec32 { RecP r; float4 v[2]; };

// ============================ kernels ============================

__global__ void k_zero(int* __restrict__ cnt, unsigned* __restrict__ state) {
    int i = blockIdx.x * blockDim.x + threadIdx.x;
    if (i < NN) cnt[i] = 0;
    if (i < NPARTS) state[i] = 0;
}

// fused: [0,EBLK): pos atomics | then M3 | Wht cvt+transpose | Xh cvt.
__global__ __launch_bounds__(256) void k_prep2(const float* __restrict__ h,
        const int* __restrict__ dst,
        const float* __restrict__ We0, const float* __restrict__ ae0,
        const float* __restrict__ We1, const float* __restrict__ ae1,
        const float* __restrict__ We2, const float* __restrict__ ae2,
        const float* __restrict__ W0, const float* __restrict__ W1,
        const float* __restrict__ W2,
        int* __restrict__ cnt, int* __restrict__ pos_loc, float* __restrict__ M,
        _Float16* __restrict__ Wht, _Float16* __restrict__ Xh) {
    int b = blockIdx.x;
    const int t = threadIdx.x;
    if (b < EBLK) {
        int e = b * 256 + t;
        if (e < NE) pos_loc[e] = atomicAdd(&cnt[dst[e]], 1);
        return;
    }
    b -= EBLK;
    if (b < 3) {
        int l = b;
        const float* We = (l == 0) ? We0 : (l == 1) ? We1 : We2;
        const float* ae = (l == 0) ? ae0 : (l == 1) ? ae1 : ae2;
        int H = (l == 2) ? 1 : 4, D = (l == 2) ? 128 : 32;
        if (t < EF_DIM * H) {
            int f = t / H, hh = t % H;
            float s = 0.f;
            for (int d = 0; d < D; d++) s += We[f * HD + hh * D + d] * ae[hh * D + d];
            M[l * 64 + f * H + hh] = s;
        }
        return;
    }
    if (b < 195) {
        int i = (b - 3) * 256 + t;       // over 3*128*128
        int l = i >> 14, rem = i & 16383;
        int n = rem >> 7, k = rem & 127;
        const float* W = (l == 0) ? W0 : (l == 1) ? W1 : W2;
        Wht[(size_t)l * 16384 + n * 128 + k] = (_Float16)W[k * 128 + n];
        return;
    }
    {
        int i = (b - 195) * 256 + t;     // over NN*32 float4's
        if (i < NN * 32) {
            float4 v = ((const float4*)h)[i];
            f16x4 o = {(_Float16)v.x, (_Float16)v.y, (_Float16)v.z, (_Float16)v.w};
            ((f16x4*)Xh)[i] = o;
        }
    }
}

// single-kernel decoupled-lookback scan: cnt -> row_ptr (exclusive).
// 196 blocks <= 256 CUs: all co-resident, spin-lookback cannot deadlock.
// state[b]: bits 30-31 flag (0 none / 1 aggregate / 2 prefix), bits 0-29 value.
__global__ __launch_bounds__(SCAN_B) void k_scan_lb(const int* __restrict__ cnt,
                                                    int* __restrict__ row_ptr,
                                                    unsigned* __restrict__ state) {
    __shared__ int s[SCAN_B];
    __shared__ int s_excl;
    const int b = blockIdx.x, t = threadIdx.x;
    const int i = b * SCAN_B + t;
    int v = (i < NN) ? cnt[i] : 0;
    s[t] = v;
    __syncthreads();
    for (int off = 1; off < SCAN_B; off <<= 1) {
        int u = (t >= off) ? s[t - off] : 0;
        __syncthreads();
        s[t] += u;
        __syncthreads();
    }
    const int agg = s[SCAN_B - 1];
    if (t == 0) {
        if (b == 0) {
            atomicExch(&state[0], (2u << 30) | (unsigned)agg);
            s_excl = 0;
        } else {
            atomicExch(&state[b], (1u << 30) | (unsigned)agg);
            int excl = 0;
            int j = b - 1;
            while (true) {
                unsigned st = atomicAdd(&state[j], 0u);  // atomic load
                unsigned flag = st >> 30;
                if (flag == 0u) continue;                // spin
                excl += (int)(st & 0x3FFFFFFFu);
                if (flag == 2u) break;
                j--;
            }
            atomicExch(&state[b], (2u << 30) | (unsigned)(excl + agg));
            s_excl = excl;
        }
    }
    __syncthreads();
    const int excl = s_excl;
    if (i < NN) row_ptr[i] = excl + s[t] - v;
    if (i == NN) row_ptr[NN] = NE;
}

// payload placement: NO atomics. Coalesced reads, fire-and-forget random 32B store.
__global__ __launch_bounds__(256) void k_place(const int* __restrict__ src,
                                               const int* __restrict__ dst,
                                               const int* __restrict__ pos_loc,
                                               const float* __restrict__ EFt,
                                               const float* __restrict__ M,
                                               const int* __restrict__ row_ptr,
                                               float4* __restrict__ rec) {
    __shared__ float sM[192];
    int t = threadIdx.x;
    if (t < 192) sM[t] = M[t];
    __syncthreads();
    int e = blockIdx.x * 256 + t;
    if (e >= NE) return;
    float ef[EF_DIM];
    const float4* efp = (const float4*)(EFt + (size_t)e * EF_DIM);
#pragma unroll
    for (int q = 0; q < 4; q++) {
        float4 v = efp[q];
        ef[4 * q] = v.x; ef[4 * q + 1] = v.y; ef[4 * q + 2] = v.z; ef[4 * q + 3] = v.w;
    }
    float o0[4] = {0.f, 0.f, 0.f, 0.f};
    float o1[4] = {0.f, 0.f, 0.f, 0.f};
    float o2 = 0.f;
#pragma unroll
    for (int f = 0; f < EF_DIM; f++) {
        float v = ef[f];
#pragma unroll
        for (int hh = 0; hh < 4; hh++) {
            o0[hh] += v * sM[f * 4 + hh];
            o1[hh] += v * sM[64 + f * 4 + hh];
        }
        o2 += v * sM[128 + f];
    }
    Rec32 u;
    u.r.src = src[e];
    u.r.e = e;
    u.r.p0 = f16x4{(_Float16)o0[0], (_Float16)o0[1], (_Float16)o0[2], (_Float16)o0[3]};
    u.r.p1 = f16x4{(_Float16)o1[0], (_Float16)o1[1], (_Float16)o1[2], (_Float16)o1[3]};
    u.r.p2 = (_Float16)o2;
    u.r.pad = (_Float16)0.f;
    int pos = row_ptr[dst[e]] + pos_loc[e];
    rec[(size_t)pos * 2] = u.v[0];
    rec[(size_t)pos * 2 + 1] = u.v[1];
}

// per-segment rank sort by (src, e) -> compact sequential SoA outputs.
__global__ __launch_bounds__(256) void k_segsort2(const int* __restrict__ row_ptr,
                                                  const float4* __restrict__ rec,
                                                  int* __restrict__ ssrc,
                                                  f16x4* __restrict__ ep0,
                                                  f16x4* __restrict__ ep1,
                                                  _Float16* __restrict__ ep2) {
    __shared__ Rec32 seg[4][128];  // 16 KB
    const int wave = threadIdx.x >> 6;
    const int lane = threadIdx.x & 63;
    const int n = blockIdx.x * 4 + wave;  // grid exactly NN/4
    const int start = row_ptr[n];
    const int len = row_ptr[n + 1] - start;
    const bool small = (len > 0 && len <= 128);
    if (small)
        for (int s = lane; s < len; s += 64) {
            seg[wave][s].v[0] = rec[(size_t)(start + s) * 2];
            seg[wave][s].v[1] = rec[(size_t)(start + s) * 2 + 1];
        }
    __syncthreads();
    if (small) {
        for (int s = lane; s < len; s += 64) {
            RecP me = seg[wave][s].r;
            int rank = 0;
            for (int j = 0; j < len; j++) {
                const RecP& o = seg[wave][j].r;
                rank += (o.src < me.src) || (o.src == me.src && o.e < me.e);
            }
            int w = start + rank;
            ssrc[w] = me.src;
            ep0[w] = me.p0;
            ep1[w] = me.p1;
            ep2[w] = me.p2;
        }
    } else if (len > 128) {  // fallback: arrival order (valid; unreachable here)
        for (int s = lane; s < len; s += 64) {
            Rec32 u;
            u.v[0] = rec[(size_t)(start + s) * 2];
            u.v[1] = rec[(size_t)(start + s) * 2 + 1];
            int w = start + s;
            ssrc[w] = u.r.src;
            ep0[w] = u.r.p0;
            ep1[w] = u.r.p1;
            ep2[w] = u.r.p2;
        }
    }
}

// feat = Xh @ W via MFMA 16x16x16 f16; fused el/er epilogue.
template <int H>
__global__ __launch_bounds__(256) void k_feat(const _Float16* __restrict__ Xh,
                                              const _Float16* __restrict__ Wht,
                                              const float* __restrict__ al,
                                              const float* __restrict__ ar,
                                              _Float16* __restrict__ Fh,
                                              float* __restrict__ el,
                                              float* __restrict__ er) {
    const int t = threadIdx.x;
    const int lane = t & 63;
    const int wv = t >> 6;
    const int l15 = lane & 15;
    const int kg = lane >> 4;
    const int nbase = blockIdx.x * 64;
    const int arow = nbase + wv * 16 + l15;
    const int rclamp = (arow < NN) ? arow : NN - 1;
    const int ksub = kg * 4;
    f16x4 a[8];
#pragma unroll
    for (int kb = 0; kb < 8; kb++)
        a[kb] = *(const f16x4*)(Xh + (size_t)rclamp * 128 + kb * 16 + ksub);

    const int r0 = nbase + wv * 16 + kg * 4;
    float slp[4][H], srp[4][H];
#pragma unroll
    for (int r = 0; r < 4; r++)
#pragma unroll
        for (int hh = 0; hh < H; hh++) { slp[r][hh] = 0.f; srp[r][hh] = 0.f; }

#pragma unroll
    for (int nt = 0; nt < 8; nt++) {
        f32x4 acc = {0.f, 0.f, 0.f, 0.f};
        const int nc = nt * 16 + l15;
        const _Float16* wp = Wht + (size_t)nc * 128;
#pragma unroll
        for (int kb = 0; kb < 8; kb++) {
            f16x4 bf = *(const f16x4*)(wp + kb * 16 + ksub);
            acc = __builtin_amdgcn_mfma_f32_16x16x16f16(a[kb], bf, acc, 0, 0, 0);
        }
        const float alv = al[nc], arv = ar[nc];
        const int hsel = (H == 4) ? (nt >> 1) : 0;
#pragma unroll
        for (int r = 0; r < 4; r++) {
            int ro = r0 + r;
            if (ro < NN) Fh[(size_t)ro * 128 + nc] = (_Float16)acc[r];
            slp[r][hsel] += acc[r] * alv;
            srp[r][hsel] += acc[r] * arv;
        }
    }

#pragma unroll
    for (int m = 1; m < 16; m <<= 1)
#pragma unroll
        for (int r = 0; r < 4; r++)
#pragma unroll
            for (int hh = 0; hh < H; hh++) {
                slp[r][hh] += __shfl_xor(slp[r][hh], m);
                srp[r][hh] += __shfl_xor(srp[r][hh], m);
            }

    if (H == 4) {
        int r = l15 >> 2, hh2 = l15 & 3;
        float sv = 0.f, ev = 0.f;
#pragma unroll
        for (int rr = 0; rr < 4; rr++)
#pragma unroll
            for (int hc = 0; hc < H; hc++)
                if (rr == r && hc == hh2) { sv = slp[rr][hc]; ev = srp[rr][hc]; }
        int ro = r0 + r;
        if (ro < NN) { el[ro * 4 + hh2] = sv; er[ro * 4 + hh2] = ev; }
    } else {
        if (l15 < 4) {
            float sv = 0.f, ev = 0.f;
#pragma unroll
            for (int rr = 0; rr < 4; rr++)
                if (rr == l15) { sv = slp[rr][0]; ev = srp[rr][0]; }
            int ro = r0 + l15;
            if (ro < NN) { el[ro] = sv; er[ro] = ev; }
        }
    }
}

// fused per-dst-node: score + softmax + aggregation. One WAVE per node.
// unroll 4 in aggregate (unroll 8 raised FETCH 95->132MB and dur +2.4us — R13 lesson).
template <int H, int D, int OUT16>
__global__ __launch_bounds__(256) void k_node(const int* __restrict__ row_ptr,
                                              const int* __restrict__ ssrc,
                                              const _Float16* __restrict__ ep,
                                              const float* __restrict__ el,
                                              const float* __restrict__ er,
                                              const __half2* __restrict__ Fh,
                                              const float* __restrict__ bias,
                                              float* __restrict__ Rf,
                                              _Float16* __restrict__ Rh,
                                              int act) {
    __shared__ float wlds[4][256];
    const int wave = threadIdx.x >> 6;
    const int lane = threadIdx.x & 63;
    const int n = blockIdx.x * 4 + wave;  // grid exactly NN/4
    const int start = row_ptr[n];
    const int end = row_ptr[n + 1];
    const int len = end - start;
    const int slots = len * H;
    const int c = 2 * lane;
    const int hcol = c / D;
    float2 b2 = make_float2(bias[c], bias[c + 1]);
    float2 a = make_float2(0.f, 0.f);

    if (len > 0) {
        constexpr int hsh = (H == 4) ? 2 : 0;
        const int hh = lane & (H - 1);
        const float er_j = er[n * H + hh];
        const _Float16* epb = ep + (size_t)start * H;
        float pmax = -3.0e38f, psum = 0.f;

        if (slots <= 256) {
            float* wp = wlds[wave];
            for (int jj = lane; jj < slots; jj += 64) {
                int i = start + (jj >> hsh);
                float x = el[ssrc[i] * H + hh] + er_j + (float)epb[jj];
                x = (x > 0.f) ? x : 0.2f * x;
                wp[jj] = x;
                pmax = fmaxf(pmax, x);
            }
            for (int m = H; m < 64; m <<= 1) pmax = fmaxf(pmax, __shfl_xor(pmax, m));
            for (int jj = lane; jj < slots; jj += 64) {
                float ex = __expf(wp[jj] - pmax);
                wp[jj] = ex;
                psum += ex;
            }
            for (int m = H; m < 64; m <<= 1) psum += __shfl_xor(psum, m);
            const float inv = 1.f / __shfl(psum, hcol);
#pragma unroll 4
            for (int i = start; i < end; i++) {
                float w = wp[(i - start) * H + hcol];
                float2 f2 = __half22float2(Fh[(size_t)ssrc[i] * 64 + lane]);
                a.x += f2.x * w;
                a.y += f2.y * w;
            }
            a.x *= inv;
            a.y *= inv;
        } else {  // recompute fallback (unreachable for this fixed graph)
            for (int jj = lane; jj < slots; jj += 64) {
                int i = start + (jj >> hsh);
                float x = el[ssrc[i] * H + hh] + er_j + (float)epb[jj];
                x = (x > 0.f) ? x : 0.2f * x;
                pmax = fmaxf(pmax, x);
            }
            for (int m = H; m < 64; m <<= 1) pmax = fmaxf(pmax, __shfl_xor(pmax, m));
            for (int jj = lane; jj < slots; jj += 64) {
                int i = start + (jj >> hsh);
                float x = el[ssrc[i] * H + hh] + er_j + (float)epb[jj];
                x = (x > 0.f) ? x : 0.2f * x;
                psum += __expf(x - pmax);
            }
            for (int m = H; m < 64; m <<= 1) psum += __shfl_xor(psum, m);
            const float inv = 1.f / __shfl(psum, hcol);
            const float pm_c = __shfl(pmax, hcol);
            const float er_c = er[n * H + hcol];
            for (int i = start; i < end; i++) {
                int sn = ssrc[i];
                float x = el[sn * H + hcol] + er_c + (float)epb[(i - start) * H + hcol];
                x = (x > 0.f) ? x : 0.2f * x;
                float w = __expf(x - pm_c);
                float2 f2 = __half22float2(Fh[(size_t)sn * 64 + lane]);
                a.x += f2.x * w;
                a.y += f2.y * w;
            }
            a.x *= inv;
            a.y *= inv;
        }
    }

    float2 v = make_float2(a.x + b2.x, a.y + b2.y);
    if (act) { v.x = fmaxf(v.x, 0.f); v.y = fmaxf(v.y, 0.f); }
    if (OUT16)
        ((__half2*)Rh)[(size_t)n * 64 + lane] = __floats2half2_rn(v.x, v.y);
    else
        ((float2*)Rf)[(size_t)n * 64 + lane] = v;
}

// ============================ driver ============================

extern "C" void kernel_launch(void* const* d_in, const int* in_sizes, int n_in,
                              void* d_out, int out_size, void* d_ws, size_t ws_size,
                              hipStream_t stream) {
    const float* h   = (const float*)d_in[0];
    const float* eft = (const float*)d_in[1];
    const int* src   = (const int*)d_in[2];
    const int* dst   = (const int*)d_in[3];
    auto P = [&](int i) { return (const float*)d_in[i]; };

    float* ws = (float*)d_ws;
    // Layout (pointer-arithmetic chained — NO overlaps):
    float4* rec    = (float4*)ws;                       // NE*32B = 6.4M f
    _Float16* Xh   = (_Float16*)(ws + 6400000);         // NN*128 halves
    _Float16* Wht  = Xh + (size_t)NN * 128;             // 3*16384 halves
    _Float16* ep0s = Wht + 3 * 16384;                   // NE*4 halves
    _Float16* ep1s = ep0s + (size_t)NE * 4;             // NE*4 halves
    _Float16* ep2s = ep1s + (size_t)NE * 4;             // NE halves
    int* ssrc      = (int*)(ep2s + NE);                 // NE ints
    int* pos_loc   = ssrc + NE;                         // NE ints
    float* M       = (float*)(pos_loc + NE);            // 192 f
    int* row_ptr   = (int*)(M + 192);                   // NN+1
    int* cnt       = row_ptr + (NN + 1);                // NN
    unsigned* state = (unsigned*)(cnt + NN);            // NPARTS
    _Float16* Fh   = (_Float16*)(state + NPARTS + 64);  // NN*128 halves
    float* el      = (float*)(Fh + (size_t)NN * 128);   // NN*4 f
    float* er      = el + (size_t)NN * 4;               // NN*4 f
    float* out     = (float*)d_out;

    // ---- CSR build + prep ----
    hipLaunchKernelGGL(k_zero, dim3(NPARTS), dim3(256), 0, stream, cnt, state);
    hipLaunchKernelGGL(k_prep2, dim3(EBLK + 195 + (NN * 32 + 255) / 256), dim3(256), 0,
                       stream, h, dst, P(5), P(8), P(11), P(14), P(17), P(20),
                       P(4), P(10), P(16), cnt, pos_loc, M, Wht, Xh);
    hipLaunchKernelGGL(k_scan_lb, dim3(NPARTS), dim3(SCAN_B), 0, stream,
                       cnt, row_ptr, state);
    hipLaunchKernelGGL(k_place, dim3(EBLK), dim3(256), 0, stream,
                       src, dst, pos_loc, eft, M, row_ptr, rec);
    hipLaunchKernelGGL(k_segsort2, dim3(NN / 4), dim3(256), 0, stream,
                       row_ptr, rec, ssrc, (f16x4*)ep0s, (f16x4*)ep1s, ep2s);

    // layer 0 (feat right before node: keep Fh/el/er hot in L2 — R13 lesson)
    hipLaunchKernelGGL((k_feat<4>), dim3(FG), dim3(256), 0, stream,
                       Xh, Wht, P(6), P(7), Fh, el, er);
    hipLaunchKernelGGL((k_node<4, 32, 1>), dim3(NN / 4), dim3(256), 0, stream,
                       row_ptr, ssrc, ep0s, el, er, (const __half2*)Fh, P(9),
                       nullptr, Xh, 1);
    // layer 1
    hipLaunchKernelGGL((k_feat<4>), dim3(FG), dim3(256), 0, stream,
                       Xh, Wht + 16384, P(12), P(13), Fh, el, er);
    hipLaunchKernelGGL((k_node<4, 32, 1>), dim3(NN / 4), dim3(256), 0, stream,
                       row_ptr, ssrc, ep1s, el, er, (const __half2*)Fh, P(15),
                       nullptr, Xh, 1);
    // layer 2: -> out (fp32, no act)
    hipLaunchKernelGGL((k_feat<1>), dim3(FG), dim3(256), 0, stream,
                       Xh, Wht + 32768, P(18), P(19), Fh, el, er);
    hipLaunchKernelGGL((k_node<1, 128, 0>), dim3(NN / 4), dim3(256), 0, stream,
                       row_ptr, ssrc, ep2s, el, er, (const __half2*)Fh, P(21),
                       out, nullptr, 0);
}

// Round 15
// 362.471 us; speedup vs baseline: 1.0582x; 1.0582x over previous
//
#include <hip/hip_runtime.h>
#include <hip/hip_fp16.h>
#include <cstdint>

#define NN 50000
#define NE 800000
static constexpr int HD = 128;     // H*D for every layer
static constexpr int EF_DIM = 16;  // edge feature dim
static constexpr int SCAN_B = 256;
static constexpr int NPARTS = (NN + SCAN_B - 1) / SCAN_B;  // 196
static constexpr int EBLK = (NE + 255) / 256;              // 3125
static constexpr int FG = (NN + 63) / 64;                  // 782 feat blocks

typedef _Float16 f16x4 __attribute__((ext_vector_type(4)));
typedef float f32x4 __attribute__((ext_vector_type(4)));

// 32B edge payload
struct RecP {
    int src;
    int e;
    f16x4 p0;       // layer0 ep (4 heads)
    f16x4 p1;       // layer1 ep
    _Float16 p2;    // layer2 ep
    _Float16 pad;
};
union Rec32 { RecP r; float4 v[2]; };

// ============================ kernels ============================

__global__ void k_zero(int* __restrict__ cnt) {
    int i = blockIdx.x * blockDim.x + threadIdx.x;
    if (i < NN) cnt[i] = 0;
}

// fused: [0,EBLK): pos atomics | then M3 | Wht cvt+transpose | Xh cvt.
__global__ __launch_bounds__(256) void k_prep2(const float* __restrict__ h,
        const int* __restrict__ dst,
        const float* __restrict__ We0, const float* __restrict__ ae0,
        const float* __restrict__ We1, const float* __restrict__ ae1,
        const float* __restrict__ We2, const float* __restrict__ ae2,
        const float* __restrict__ W0, const float* __restrict__ W1,
        const float* __restrict__ W2,
        int* __restrict__ cnt, int* __restrict__ pos_loc, float* __restrict__ M,
        _Float16* __restrict__ Wht, _Float16* __restrict__ Xh) {
    int b = blockIdx.x;
    const int t = threadIdx.x;
    if (b < EBLK) {
        int e = b * 256 + t;
        if (e < NE) pos_loc[e] = atomicAdd(&cnt[dst[e]], 1);
        return;
    }
    b -= EBLK;
    if (b < 3) {
        int l = b;
        const float* We = (l == 0) ? We0 : (l == 1) ? We1 : We2;
        const float* ae = (l == 0) ? ae0 : (l == 1) ? ae1 : ae2;
        int H = (l == 2) ? 1 : 4, D = (l == 2) ? 128 : 32;
        if (t < EF_DIM * H) {
            int f = t / H, hh = t % H;
            float s = 0.f;
            for (int d = 0; d < D; d++) s += We[f * HD + hh * D + d] * ae[hh * D + d];
            M[l * 64 + f * H + hh] = s;
        }
        return;
    }
    if (b < 195) {
        int i = (b - 3) * 256 + t;       // over 3*128*128
        int l = i >> 14, rem = i & 16383;
        int n = rem >> 7, k = rem & 127;
        const float* W = (l == 0) ? W0 : (l == 1) ? W1 : W2;
        Wht[(size_t)l * 16384 + n * 128 + k] = (_Float16)W[k * 128 + n];
        return;
    }
    {
        int i = (b - 195) * 256 + t;     // over NN*32 float4's
        if (i < NN * 32) {
            float4 v = ((const float4*)h)[i];
            f16x4 o = {(_Float16)v.x, (_Float16)v.y, (_Float16)v.z, (_Float16)v.w};
            ((f16x4*)Xh)[i] = o;
        }
    }
}

__global__ __launch_bounds__(SCAN_B) void k_part(const int* __restrict__ deg,
                                                 int* __restrict__ part) {
    __shared__ int s[SCAN_B];
    int t = threadIdx.x;
    int i = blockIdx.x * SCAN_B + t;
    s[t] = (i < NN) ? deg[i] : 0;
    __syncthreads();
    for (int off = SCAN_B / 2; off > 0; off >>= 1) {
        if (t < off) s[t] += s[t + off];
        __syncthreads();
    }
    if (t == 0) part[blockIdx.x] = s[0];
}

__global__ __launch_bounds__(SCAN_B) void k_scanpart(int* __restrict__ part) {
    __shared__ int s[SCAN_B];
    int t = threadIdx.x;
    int v = (t < NPARTS) ? part[t] : 0;
    s[t] = v;
    __syncthreads();
    for (int off = 1; off < SCAN_B; off <<= 1) {
        int u = (t >= off) ? s[t - off] : 0;
        __syncthreads();
        s[t] += u;
        __syncthreads();
    }
    if (t < NPARTS) part[t] = s[t] - v;  // exclusive
}

__global__ __launch_bounds__(SCAN_B) void k_rowptr(const int* __restrict__ deg,
                                                   const int* __restrict__ part,
                                                   int* __restrict__ row_ptr) {
    __shared__ int s[SCAN_B];
    int t = threadIdx.x;
    int i = blockIdx.x * SCAN_B + t;
    int v = (i < NN) ? deg[i] : 0;
    s[t] = v;
    __syncthreads();
    for (int off = 1; off < SCAN_B; off <<= 1) {
        int u = (t >= off) ? s[t - off] : 0;
        __syncthreads();
        s[t] += u;
        __syncthreads();
    }
    int excl = s[t] - v + part[blockIdx.x];
    if (i < NN) row_ptr[i] = excl;
    if (i == NN) row_ptr[NN] = NE;
}

// payload placement: NO atomics. Coalesced reads, fire-and-forget random 32B store.
__global__ __launch_bounds__(256) void k_place(const int* __restrict__ src,
                                               const int* __restrict__ dst,
                                               const int* __restrict__ pos_loc,
                                               const float* __restrict__ EFt,
                                               const float* __restrict__ M,
                                               const int* __restrict__ row_ptr,
                                               float4* __restrict__ rec) {
    __shared__ float sM[192];
    int t = threadIdx.x;
    if (t < 192) sM[t] = M[t];
    __syncthreads();
    int e = blockIdx.x * 256 + t;
    if (e >= NE) return;
    float ef[EF_DIM];
    const float4* efp = (const float4*)(EFt + (size_t)e * EF_DIM);
#pragma unroll
    for (int q = 0; q < 4; q++) {
        float4 v = efp[q];
        ef[4 * q] = v.x; ef[4 * q + 1] = v.y; ef[4 * q + 2] = v.z; ef[4 * q + 3] = v.w;
    }
    float o0[4] = {0.f, 0.f, 0.f, 0.f};
    float o1[4] = {0.f, 0.f, 0.f, 0.f};
    float o2 = 0.f;
#pragma unroll
    for (int f = 0; f < EF_DIM; f++) {
        float v = ef[f];
#pragma unroll
        for (int hh = 0; hh < 4; hh++) {
            o0[hh] += v * sM[f * 4 + hh];
            o1[hh] += v * sM[64 + f * 4 + hh];
        }
        o2 += v * sM[128 + f];
    }
    Rec32 u;
    u.r.src = src[e];
    u.r.e = e;
    u.r.p0 = f16x4{(_Float16)o0[0], (_Float16)o0[1], (_Float16)o0[2], (_Float16)o0[3]};
    u.r.p1 = f16x4{(_Float16)o1[0], (_Float16)o1[1], (_Float16)o1[2], (_Float16)o1[3]};
    u.r.p2 = (_Float16)o2;
    u.r.pad = (_Float16)0.f;
    int pos = row_ptr[dst[e]] + pos_loc[e];
    rec[(size_t)pos * 2] = u.v[0];
    rec[(size_t)pos * 2 + 1] = u.v[1];
}

// per-segment rank sort by (src, e) -> compact sequential SoA outputs.
__global__ __launch_bounds__(256) void k_segsort2(const int* __restrict__ row_ptr,
                                                  const float4* __restrict__ rec,
                                                  int* __restrict__ ssrc,
                                                  f16x4* __restrict__ ep0,
                                                  f16x4* __restrict__ ep1,
                                                  _Float16* __restrict__ ep2) {
    __shared__ Rec32 seg[4][128];  // 16 KB
    const int wave = threadIdx.x >> 6;
    const int lane = threadIdx.x & 63;
    const int n = blockIdx.x * 4 + wave;  // grid exactly NN/4
    const int start = row_ptr[n];
    const int len = row_ptr[n + 1] - start;
    const bool small = (len > 0 && len <= 128);
    if (small)
        for (int s = lane; s < len; s += 64) {
            seg[wave][s].v[0] = rec[(size_t)(start + s) * 2];
            seg[wave][s].v[1] = rec[(size_t)(start + s) * 2 + 1];
        }
    __syncthreads();
    if (small) {
        for (int s = lane; s < len; s += 64) {
            RecP me = seg[wave][s].r;
            int rank = 0;
            for (int j = 0; j < len; j++) {
                const RecP& o = seg[wave][j].r;
                rank += (o.src < me.src) || (o.src == me.src && o.e < me.e);
            }
            int w = start + rank;
            ssrc[w] = me.src;
            ep0[w] = me.p0;
            ep1[w] = me.p1;
            ep2[w] = me.p2;
        }
    } else if (len > 128) {  // fallback: arrival order (valid; unreachable here)
        for (int s = lane; s < len; s += 64) {
            Rec32 u;
            u.v[0] = rec[(size_t)(start + s) * 2];
            u.v[1] = rec[(size_t)(start + s) * 2 + 1];
            int w = start + s;
            ssrc[w] = u.r.src;
            ep0[w] = u.r.p0;
            ep1[w] = u.r.p1;
            ep2[w] = u.r.p2;
        }
    }
}

// feat = Xh @ W via MFMA 16x16x16 f16; fused el/er epilogue.
template <int H>
__global__ __launch_bounds__(256) void k_feat(const _Float16* __restrict__ Xh,
                                              const _Float16* __restrict__ Wht,
                                              const float* __restrict__ al,
                                              const float* __restrict__ ar,
                                              _Float16* __restrict__ Fh,
                                              float* __restrict__ el,
                                              float* __restrict__ er) {
    const int t = threadIdx.x;
    const int lane = t & 63;
    const int wv = t >> 6;
    const int l15 = lane & 15;
    const int kg = lane >> 4;
    const int nbase = blockIdx.x * 64;
    const int arow = nbase + wv * 16 + l15;
    const int rclamp = (arow < NN) ? arow : NN - 1;
    const int ksub = kg * 4;
    f16x4 a[8];
#pragma unroll
    for (int kb = 0; kb < 8; kb++)
        a[kb] = *(const f16x4*)(Xh + (size_t)rclamp * 128 + kb * 16 + ksub);

    const int r0 = nbase + wv * 16 + kg * 4;
    float slp[4][H], srp[4][H];
#pragma unroll
    for (int r = 0; r < 4; r++)
#pragma unroll
        for (int hh = 0; hh < H; hh++) { slp[r][hh] = 0.f; srp[r][hh] = 0.f; }

#pragma unroll
    for (int nt = 0; nt < 8; nt++) {
        f32x4 acc = {0.f, 0.f, 0.f, 0.f};
        const int nc = nt * 16 + l15;
        const _Float16* wp = Wht + (size_t)nc * 128;
#pragma unroll
        for (int kb = 0; kb < 8; kb++) {
            f16x4 bf = *(const f16x4*)(wp + kb * 16 + ksub);
            acc = __builtin_amdgcn_mfma_f32_16x16x16f16(a[kb], bf, acc, 0, 0, 0);
        }
        const float alv = al[nc], arv = ar[nc];
        const int hsel = (H == 4) ? (nt >> 1) : 0;
#pragma unroll
        for (int r = 0; r < 4; r++) {
            int ro = r0 + r;
            if (ro < NN) Fh[(size_t)ro * 128 + nc] = (_Float16)acc[r];
            slp[r][hsel] += acc[r] * alv;
            srp[r][hsel] += acc[r] * arv;
        }
    }

#pragma unroll
    for (int m = 1; m < 16; m <<= 1)
#pragma unroll
        for (int r = 0; r < 4; r++)
#pragma unroll
            for (int hh = 0; hh < H; hh++) {
                slp[r][hh] += __shfl_xor(slp[r][hh], m);
                srp[r][hh] += __shfl_xor(srp[r][hh], m);
            }

    if (H == 4) {
        int r = l15 >> 2, hh2 = l15 & 3;
        float sv = 0.f, ev = 0.f;
#pragma unroll
        for (int rr = 0; rr < 4; rr++)
#pragma unroll
            for (int hc = 0; hc < H; hc++)
                if (rr == r && hc == hh2) { sv = slp[rr][hc]; ev = srp[rr][hc]; }
        int ro = r0 + r;
        if (ro < NN) { el[ro * 4 + hh2] = sv; er[ro * 4 + hh2] = ev; }
    } else {
        if (l15 < 4) {
            float sv = 0.f, ev = 0.f;
#pragma unroll
            for (int rr = 0; rr < 4; rr++)
                if (rr == l15) { sv = slp[rr][0]; ev = srp[rr][0]; }
            int ro = r0 + l15;
            if (ro < NN) { el[ro] = sv; er[ro] = ev; }
        }
    }
}

// fused per-dst-node: score + softmax + aggregation. One WAVE per node.
template <int H, int D, int OUT16>
__global__ __launch_bounds__(256) void k_node(const int* __restrict__ row_ptr,
                                              const int* __restrict__ ssrc,
                                              const _Float16* __restrict__ ep,
                                              const float* __restrict__ el,
                                              const float* __restrict__ er,
                                              const __half2* __restrict__ Fh,
                                              const float* __restrict__ bias,
                                              float* __restrict__ Rf,
                                              _Float16* __restrict__ Rh,
                                              int act) {
    __shared__ float wlds[4][256];
    const int wave = threadIdx.x >> 6;
    const int lane = threadIdx.x & 63;
    const int n = blockIdx.x * 4 + wave;  // grid exactly NN/4
    const int start = row_ptr[n];
    const int end = row_ptr[n + 1];
    const int len = end - start;
    const int slots = len * H;
    const int c = 2 * lane;
    const int hcol = c / D;
    float2 b2 = make_float2(bias[c], bias[c + 1]);
    float2 a = make_float2(0.f, 0.f);

    if (len > 0) {
        constexpr int hsh = (H == 4) ? 2 : 0;
        const int hh = lane & (H - 1);
        const float er_j = er[n * H + hh];
        const _Float16* epb = ep + (size_t)start * H;
        float pmax = -3.0e38f, psum = 0.f;

        if (slots <= 256) {
            float* wp = wlds[wave];
            for (int jj = lane; jj < slots; jj += 64) {
                int i = start + (jj >> hsh);
                float x = el[ssrc[i] * H + hh] + er_j + (float)epb[jj];
                x = (x > 0.f) ? x : 0.2f * x;
                wp[jj] = x;
                pmax = fmaxf(pmax, x);
            }
            for (int m = H; m < 64; m <<= 1) pmax = fmaxf(pmax, __shfl_xor(pmax, m));
            for (int jj = lane; jj < slots; jj += 64) {
                float ex = __expf(wp[jj] - pmax);
                wp[jj] = ex;
                psum += ex;
            }
            for (int m = H; m < 64; m <<= 1) psum += __shfl_xor(psum, m);
            const float inv = 1.f / __shfl(psum, hcol);
#pragma unroll 4
            for (int i = start; i < end; i++) {
                float w = wp[(i - start) * H + hcol];
                float2 f2 = __half22float2(Fh[(size_t)ssrc[i] * 64 + lane]);
                a.x += f2.x * w;
                a.y += f2.y * w;
            }
            a.x *= inv;
            a.y *= inv;
        } else {  // recompute fallback (unreachable for this fixed graph)
            for (int jj = lane; jj < slots; jj += 64) {
                int i = start + (jj >> hsh);
                float x = el[ssrc[i] * H + hh] + er_j + (float)epb[jj];
                x = (x > 0.f) ? x : 0.2f * x;
                pmax = fmaxf(pmax, x);
            }
            for (int m = H; m < 64; m <<= 1) pmax = fmaxf(pmax, __shfl_xor(pmax, m));
            for (int jj = lane; jj < slots; jj += 64) {
                int i = start + (jj >> hsh);
                float x = el[ssrc[i] * H + hh] + er_j + (float)epb[jj];
                x = (x > 0.f) ? x : 0.2f * x;
                psum += __expf(x - pmax);
            }
            for (int m = H; m < 64; m <<= 1) psum += __shfl_xor(psum, m);
            const float inv = 1.f / __shfl(psum, hcol);
            const float pm_c = __shfl(pmax, hcol);
            const float er_c = er[n * H + hcol];
            for (int i = start; i < end; i++) {
                int sn = ssrc[i];
                float x = el[sn * H + hcol] + er_c + (float)epb[(i - start) * H + hcol];
                x = (x > 0.f) ? x : 0.2f * x;
                float w = __expf(x - pm_c);
                float2 f2 = __half22float2(Fh[(size_t)sn * 64 + lane]);
                a.x += f2.x * w;
                a.y += f2.y * w;
            }
            a.x *= inv;
            a.y *= inv;
        }
    }

    float2 v = make_float2(a.x + b2.x, a.y + b2.y);
    if (act) { v.x = fmaxf(v.x, 0.f); v.y = fmaxf(v.y, 0.f); }
    if (OUT16)
        ((__half2*)Rh)[(size_t)n * 64 + lane] = __floats2half2_rn(v.x, v.y);
    else
        ((float2*)Rf)[(size_t)n * 64 + lane] = v;
}

// ============================ driver ============================

extern "C" void kernel_launch(void* const* d_in, const int* in_sizes, int n_in,
                              void* d_out, int out_size, void* d_ws, size_t ws_size,
                              hipStream_t stream) {
    const float* h   = (const float*)d_in[0];
    const float* eft = (const float*)d_in[1];
    const int* src   = (const int*)d_in[2];
    const int* dst   = (const int*)d_in[3];
    auto P = [&](int i) { return (const float*)d_in[i]; };

    float* ws = (float*)d_ws;
    // R10's measured-best layout: Fh/el/er OVERLAY rec (rec dead after segsort2;
    // feat writes into L2-hot lines right before node's gather — FETCH 95 vs 133 MB).
    float4* rec    = (float4*)ws;                       // [0, 6.4M floats)
    _Float16* Fh   = (_Float16*)ws;                     // overlay [0, 3.2M f)
    float* el      = ws + 3200000;                      // overlay [3.2M, 3.4M)
    float* er      = ws + 3400000;                      // overlay [3.4M, 3.6M)
    _Float16* Xh   = (_Float16*)(ws + 6400000);         // [6.4M, 9.6M)
    _Float16* Wht  = Xh + (size_t)NN * 128;             // 3*16384 halves
    _Float16* ep0s = Wht + 3 * 16384;                   // NE*4 halves
    _Float16* ep1s = ep0s + (size_t)NE * 4;             // NE*4 halves
    _Float16* ep2s = ep1s + (size_t)NE * 4;             // NE halves
    int* ssrc      = (int*)(ep2s + NE);                 // NE ints
    int* pos_loc   = ssrc + NE;                         // NE ints
    float* M       = (float*)(pos_loc + NE);            // 192 f
    int* row_ptr   = (int*)(M + 192);                   // NN+1
    int* cnt       = row_ptr + (NN + 1);                // NN
    int* part      = cnt + NN;                          // NPARTS
    float* out     = (float*)d_out;

    // ---- CSR build + prep ----
    hipLaunchKernelGGL(k_zero, dim3(NPARTS), dim3(256), 0, stream, cnt);
    hipLaunchKernelGGL(k_prep2, dim3(EBLK + 195 + (NN * 32 + 255) / 256), dim3(256), 0,
                       stream, h, dst, P(5), P(8), P(11), P(14), P(17), P(20),
                       P(4), P(10), P(16), cnt, pos_loc, M, Wht, Xh);
    hipLaunchKernelGGL(k_part, dim3(NPARTS), dim3(SCAN_B), 0, stream, cnt, part);
    hipLaunchKernelGGL(k_scanpart, dim3(1), dim3(SCAN_B), 0, stream, part);
    hipLaunchKernelGGL(k_rowptr, dim3(NPARTS), dim3(SCAN_B), 0, stream,
                       cnt, part, row_ptr);
    hipLaunchKernelGGL(k_place, dim3(EBLK), dim3(256), 0, stream,
                       src, dst, pos_loc, eft, M, row_ptr, rec);
    hipLaunchKernelGGL(k_segsort2, dim3(NN / 4), dim3(256), 0, stream,
                       row_ptr, rec, ssrc, (f16x4*)ep0s, (f16x4*)ep1s, ep2s);

    // layer 0 (feat right before node: Fh/el/er written into L2-hot rec lines)
    hipLaunchKernelGGL((k_feat<4>), dim3(FG), dim3(256), 0, stream,
                       Xh, Wht, P(6), P(7), Fh, el, er);
    hipLaunchKernelGGL((k_node<4, 32, 1>), dim3(NN / 4), dim3(256), 0, stream,
                       row_ptr, ssrc, ep0s, el, er, (const __half2*)Fh, P(9),
                       nullptr, Xh, 1);
    // layer 1
    hipLaunchKernelGGL((k_feat<4>), dim3(FG), dim3(256), 0, stream,
                       Xh, Wht + 16384, P(12), P(13), Fh, el, er);
    hipLaunchKernelGGL((k_node<4, 32, 1>), dim3(NN / 4), dim3(256), 0, stream,
                       row_ptr, ssrc, ep1s, el, er, (const __half2*)Fh, P(15),
                       nullptr, Xh, 1);
    // layer 2: -> out (fp32, no act)
    hipLaunchKernelGGL((k_feat<1>), dim3(FG), dim3(256), 0, stream,
                       Xh, Wht + 32768, P(18), P(19), Fh, el, er);
    hipLaunchKernelGGL((k_node<1, 128, 0>), dim3(NN / 4), dim3(256), 0, stream,
                       row_ptr, ssrc, ep2s, el, er, (const __half2*)Fh, P(21),
                       out, nullptr, 0);
}